// Round 9
// baseline (167.691 us; speedup 1.0000x reference)
//
#include <hip/hip_runtime.h>
#include <math.h>

#define BATCH 4
#define CH    256
#define NPIX  4096
#define DQK   32

typedef short          s16;
typedef unsigned int   uint_t;
typedef __attribute__((ext_vector_type(8)))  short short8;    // 8 bf16
typedef __attribute__((ext_vector_type(4)))  float floatx4;   // 16x16 C/D
typedef __attribute__((ext_vector_type(16))) float floatx16;  // 32x32 C/D

__device__ __forceinline__ s16 f2bf(float f) {
  union { float f; uint_t u; } v; v.f = f;
  return (s16)((v.u + 0x8000u) >> 16);
}
__device__ __forceinline__ float bf2f(s16 u) {
  union { uint_t u; float f; } v; v.u = ((uint_t)(unsigned short)u) << 16; return v.f;
}
__device__ __forceinline__ uint_t pk2(float a, float b) {
  union { float f; uint_t u; } x, y; x.f = a; y.f = b;
  return (((y.u + 0x8000u) >> 16) << 16) | ((x.u + 0x8000u) >> 16);
}

// ======== prepack2: W -> Wt in exact B-frag order; biases -> Bsw ==========
// Wt[(kc*320 + n)*8 + j] = bf16(Wcat[n][kc*8+j]), kc=0..31, n=0..319.
// Store address = gid*8 -> perfectly contiguous stores.
__global__ __launch_bounds__(256) void prepack2(
    const float* __restrict__ Wq, const float* __restrict__ bq,
    const float* __restrict__ Wk, const float* __restrict__ bk,
    const float* __restrict__ Wv, const float* __restrict__ bv,
    s16* __restrict__ Wt, float* __restrict__ Bsw)
{
  const int gid = blockIdx.x * 256 + threadIdx.x;   // grid 40 -> 10240
  const int kc  = gid / 320;
  const int n   = gid - kc * 320;
  const float* src = (n < 32) ? Wq + (size_t)n * 256
                   : (n < 64) ? Wk + (size_t)(n - 32) * 256
                              : Wv + (size_t)(n - 64) * 256;
  float4 f0 = *(const float4*)(src + kc * 8);
  float4 f1 = *(const float4*)(src + kc * 8 + 4);
  uint4 o;
  o.x = pk2(f0.x, f0.y); o.y = pk2(f0.z, f0.w);
  o.z = pk2(f1.x, f1.y); o.w = pk2(f1.z, f1.w);
  *(uint4*)(Wt + (size_t)gid * 8) = o;
  if (gid < 320)
    Bsw[gid] = (gid < 32) ? bq[gid] : (gid < 64) ? bk[gid - 32] : bv[gid - 64];
}

// ======== xtrans: x [b][c][n] fp32 -> Xt [b][n][c] bf16 (coalesced) =======
// grid 1024 = b(4) x c0(4) x ntile(64); 64x64 tiles via LDS (pad 65: no conflicts).
__global__ __launch_bounds__(256) void xtrans(
    const float* __restrict__ x, s16* __restrict__ Xt)
{
  const int bi = blockIdx.x;
  const int b  = bi >> 8;
  const int c0 = ((bi >> 6) & 3) * 64;
  const int n0 = (bi & 63) * 64;
  const int t  = threadIdx.x;

  __shared__ float Ls[64][65];

  const float* xb = x + ((size_t)b * CH + c0) * NPIX + n0;
  #pragma unroll
  for (int rep = 0; rep < 4; ++rep) {
    const int task = rep * 256 + t;           // 1024 = 64c x 16pg
    const int pg = task & 15, c = task >> 4;
    float4 f = *(const float4*)(xb + (size_t)c * NPIX + pg * 4);
    Ls[c][pg * 4 + 0] = f.x; Ls[c][pg * 4 + 1] = f.y;
    Ls[c][pg * 4 + 2] = f.z; Ls[c][pg * 4 + 3] = f.w;
  }
  __syncthreads();

  s16* xo = Xt + ((size_t)b * NPIX + n0) * CH + c0;
  #pragma unroll
  for (int rep = 0; rep < 2; ++rep) {
    const int cg = t & 7;
    const int n  = (t >> 3) + rep * 32;
    float f[8];
    #pragma unroll
    for (int j = 0; j < 8; ++j) f[j] = Ls[cg * 8 + j][n];
    uint4 o;
    o.x = pk2(f[0], f[1]); o.y = pk2(f[2], f[3]);
    o.z = pk2(f[4], f[5]); o.w = pk2(f[6], f[7]);
    *(uint4*)(xo + (size_t)n * CH + cg * 8) = o;   // lanes: 8x16B = 128B rows
  }
}

// ======== proj2: OUT^T[px][outrow] = Xt·W^T — no LDS, 4 blocks/CU =========
// grid 1024 = b(4) x pxtile(64) x os(4). Block: 64 px x 80 outrows.
// wave w: px-strip 16w; 5 outrow strips of 16. A from Xt, B from Wt (global).
__global__ __launch_bounds__(256, 4) void proj2(
    const s16* __restrict__ Xt, const s16* __restrict__ Wt,
    const float* __restrict__ Bsw,
    s16* __restrict__ Qw, s16* __restrict__ Kw, s16* __restrict__ Vw)
{
  const int bi = blockIdx.x;
  const int b    = bi & 3;
  const int tile = (bi >> 2) & 63;
  const int os   = bi >> 8;
  const int t  = threadIdx.x;
  const int w    = t >> 6;
  const int l15  = t & 15;
  const int quad = (t & 63) >> 4;

  const int pxw = tile * 64 + 16 * w;          // wave's px strip base
  const int ro0 = os * 80;                     // outrow base

  const s16* abase = Xt + ((size_t)b * NPIX + pxw + l15) * CH + quad * 8;
  // B addr: ((kc32*4+quad)*320 + ro0+16*st+l15)*8 ; kc32 step = 4*320*8
  const s16* bbase = Wt + ((size_t)quad * 320 + ro0 + l15) * 8;

  floatx4 acc[5];
  #pragma unroll
  for (int st = 0; st < 5; ++st) acc[st] = (floatx4){0.f, 0.f, 0.f, 0.f};

  short8 Ac, An, Bc[5], Bn[5];
  Ac = *(const short8*)(abase);
  #pragma unroll
  for (int st = 0; st < 5; ++st)
    Bc[st] = *(const short8*)(bbase + (size_t)st * 128);   // 16*8 shorts

  for (int kc = 0; kc < 8; ++kc) {
    const int kn = (kc < 7) ? kc + 1 : 7;
    An = *(const short8*)(abase + kn * 32);
    #pragma unroll
    for (int st = 0; st < 5; ++st)
      Bn[st] = *(const short8*)(bbase + (size_t)kn * 10240 + (size_t)st * 128);
    #pragma unroll
    for (int st = 0; st < 5; ++st)
      acc[st] = __builtin_amdgcn_mfma_f32_16x16x32_bf16(Ac, Bc[st], acc[st], 0, 0, 0);
    Ac = An;
    #pragma unroll
    for (int st = 0; st < 5; ++st) Bc[st] = Bn[st];
  }

  // ---- epilogue: C row = px = pxw+quad*4+r ; col = outrow = ro0+16st+l15
  #pragma unroll
  for (int st = 0; st < 5; ++st) {
    const int orow = ro0 + 16 * st + l15;
    const float bias = Bsw[orow];
    float v0 = acc[st][0] + bias, v1 = acc[st][1] + bias;
    float v2 = acc[st][2] + bias, v3 = acc[st][3] + bias;
    const int px = pxw + quad * 4;
    if (orow < 64) {                 // Q (d=orow) or K (d=orow-32): scatter 2B
      s16* dst = (orow < 32) ? Qw : Kw;
      const int d = orow & 31;
      s16* p = dst + ((size_t)b * NPIX + px) * DQK + d;
      p[0] = f2bf(v0); p[DQK] = f2bf(v1); p[2 * DQK] = f2bf(v2); p[3 * DQK] = f2bf(v3);
    } else {                         // V: 4 contiguous px -> uint2
      const int ch = orow - 64;
      uint2 o; o.x = pk2(v0, v1); o.y = pk2(v2, v3);
      *(uint2*)(Vw + ((size_t)b * CH + ch) * NPIX + px) = o;
    }
  }
}

// ============ attn: UNCHANGED r8 (key-split, 32x32 PV, bf16 partials) ======
__global__ __launch_bounds__(512, 4) void attn_mfma(
    const s16* __restrict__ Qw, const s16* __restrict__ Kw,
    const s16* __restrict__ Vw, s16* __restrict__ Op, float* __restrict__ Lp)
{
  const int bi = blockIdx.x;
  const int b  = (bi & 7) >> 1;
  const int ks = (bi >> 3) & 1;
  const int qt = ((bi >> 4) << 1) | (bi & 1);
  const int n0 = qt * 64;
  const int km0 = ks * 2048;
  const int t  = threadIdx.x;
  const int w    = t >> 6;
  const int l15  = t & 15;
  const int quad = (t & 63) >> 4;
  const int l31  = t & 31;
  const int half = (t & 63) >> 5;

  __shared__ s16  Pt[2][64][136];
  __shared__ float Lsum[64][8];

  const s16* qbase = Qw + ((size_t)b * NPIX + n0) * DQK;
  short8 qb[4];
  #pragma unroll
  for (int tq = 0; tq < 4; ++tq)
    qb[tq] = *(const short8*)(qbase + (size_t)(16 * tq + l15) * DQK + quad * 8);

  floatx16 o0, o1;
  #pragma unroll
  for (int i = 0; i < 16; ++i) { o0[i] = 0.f; o1[i] = 0.f; }
  float l_part[4] = {0.f, 0.f, 0.f, 0.f};

  const s16* kbase = Kw + ((size_t)b * NPIX + km0) * DQK;
  const s16* vrow  = Vw + ((size_t)b * CH + 32 * w + l31) * NPIX + km0;

  short8 ka_c = *(const short8*)(kbase + (size_t)(16 * w + l15) * DQK + quad * 8);
  short8 va[8];
  #pragma unroll
  for (int s = 0; s < 8; ++s)
    va[s] = *(const short8*)(vrow + s * 16 + half * 8);

  int buf = 0;
  for (int kt = 0; kt < 16; ++kt) {
    const int m0  = kt * 128;
    const int mn0 = (kt < 15) ? m0 + 128 : 0;

    floatx4 sacc[4];
    #pragma unroll
    for (int tq = 0; tq < 4; ++tq)
      sacc[tq] = __builtin_amdgcn_mfma_f32_16x16x32_bf16(
                   ka_c, qb[tq], (floatx4){0.f, 0.f, 0.f, 0.f}, 0, 0, 0);

    short8 ka_n = *(const short8*)(kbase + (size_t)(mn0 + 16 * w + l15) * DQK + quad * 8);

    #pragma unroll
    for (int tq = 0; tq < 4; ++tq) {
      float p0 = __expf(sacc[tq][0]);
      float p1 = __expf(sacc[tq][1]);
      float p2 = __expf(sacc[tq][2]);
      float p3 = __expf(sacc[tq][3]);
      float ts = (p0 + p1) + (p2 + p3);
      uint2 pk; pk.x = pk2(p0, p1); pk.y = pk2(p2, p3);
      *(uint2*)&Pt[buf][16 * tq + l15][16 * w + quad * 4] = pk;
      ts += __shfl_xor(ts, 16);
      ts += __shfl_xor(ts, 32);
      l_part[tq] += ts;
    }
    __syncthreads();

    #pragma unroll
    for (int s = 0; s < 8; ++s) {
      short8 pb0 = *(const short8*)&Pt[buf][l31][16 * s + half * 8];
      short8 pb1 = *(const short8*)&Pt[buf][32 + l31][16 * s + half * 8];
      o0 = __builtin_amdgcn_mfma_f32_32x32x16_bf16(va[s], pb0, o0, 0, 0, 0);
      o1 = __builtin_amdgcn_mfma_f32_32x32x16_bf16(va[s], pb1, o1, 0, 0, 0);
      va[s] = *(const short8*)(vrow + mn0 + 16 * s + half * 8);
    }
    ka_c = ka_n;
    buf ^= 1;
  }

  if (quad == 0) {
    #pragma unroll
    for (int tq = 0; tq < 4; ++tq) Lsum[16 * tq + l15][w] = l_part[tq];
  }
  __syncthreads();
  if (t < 64) {
    float4 s0 = *(const float4*)&Lsum[t][0];
    float4 s1 = *(const float4*)&Lsum[t][4];
    Lp[(((size_t)b * 2 + ks) * 64 + qt) * 64 + t] =
        ((s0.x + s0.y) + (s0.z + s0.w)) + ((s1.x + s1.y) + (s1.z + s1.w));
  }

  s16* ob = Op + (((size_t)b * 2 + ks) * 64 + qt) * (256 * 64);
  #pragma unroll
  for (int reg = 0; reg < 16; ++reg) {
    const int ch = 32 * w + (reg & 3) + 8 * (reg >> 2) + 4 * half;
    ob[ch * 64 + l31]      = f2bf(o0[reg]);
    ob[ch * 64 + 32 + l31] = f2bf(o1[reg]);
  }
}

// ============ merge: UNCHANGED r8 ==========================================
__global__ __launch_bounds__(256) void reduce_merge(
    const s16* __restrict__ Op, const float* __restrict__ Lp,
    const float* __restrict__ x, float* __restrict__ out)
{
  const size_t e0 = ((size_t)blockIdx.x * 256 + threadIdx.x) * 8;
  const int n  = (int)(e0 & 4095);
  const int ch = (int)((e0 >> 12) & 255);
  const int b  = (int)(e0 >> 20);
  const int qt = n >> 6, q = n & 63;

  const size_t p0 = (((size_t)b * 2 + 0) * 64 + qt) * (256 * 64) + ch * 64 + q;
  const size_t p1 = (((size_t)b * 2 + 1) * 64 + qt) * (256 * 64) + ch * 64 + q;
  union { uint4 v; s16 u[8]; } O0, O1;
  O0.v = *(const uint4*)(Op + p0);
  O1.v = *(const uint4*)(Op + p1);

  const float* l0p = Lp + (((size_t)b * 2 + 0) * 64 + qt) * 64 + q;
  const float* l1p = Lp + (((size_t)b * 2 + 1) * 64 + qt) * 64 + q;
  float4 l0a = *(const float4*)l0p, l0b = *(const float4*)(l0p + 4);
  float4 l1a = *(const float4*)l1p, l1b = *(const float4*)(l1p + 4);
  float linv[8] = {
    1.f / (l0a.x + l1a.x), 1.f / (l0a.y + l1a.y),
    1.f / (l0a.z + l1a.z), 1.f / (l0a.w + l1a.w),
    1.f / (l0b.x + l1b.x), 1.f / (l0b.y + l1b.y),
    1.f / (l0b.z + l1b.z), 1.f / (l0b.w + l1b.w) };

  float4 xa = *(const float4*)(x + e0), xb = *(const float4*)(x + e0 + 4);
  float r[8] = { xa.x, xa.y, xa.z, xa.w, xb.x, xb.y, xb.z, xb.w };
  #pragma unroll
  for (int j = 0; j < 8; ++j)
    r[j] = fmaf(bf2f(O0.u[j]) + bf2f(O1.u[j]), linv[j], r[j]);
  *(float4*)(out + e0)     = make_float4(r[0], r[1], r[2], r[3]);
  *(float4*)(out + e0 + 4) = make_float4(r[4], r[5], r[6], r[7]);
}

extern "C" void kernel_launch(void* const* d_in, const int* in_sizes, int n_in,
                              void* d_out, int out_size, void* d_ws, size_t ws_size,
                              hipStream_t stream) {
  (void)in_sizes; (void)n_in; (void)out_size; (void)ws_size;
  const float* x  = (const float*)d_in[0];
  const float* Wq = (const float*)d_in[1];
  const float* bq = (const float*)d_in[2];
  const float* Wk = (const float*)d_in[3];
  const float* bk = (const float*)d_in[4];
  const float* Wv = (const float*)d_in[5];
  const float* bv = (const float*)d_in[6];
  float* out = (float*)d_out;

  // ws (27 MiB): Qw @0 (1M) | Kw @1M (1M) | Vw @2M (8M) | Wt @10M (160K) |
  // Bsw @10M+256K | Lp @10M+512K (128K) | Xt @11M (8M, dead after proj2) |
  // Op @11M (16M, overlays Xt — written by attn after Xt is dead)
  unsigned char* ws = (unsigned char*)d_ws;
  s16*   Qw  = (s16*)ws;
  s16*   Kw  = (s16*)(ws + (size_t)1 * 1024 * 1024);
  s16*   Vw  = (s16*)(ws + (size_t)2 * 1024 * 1024);
  s16*   Wt  = (s16*)(ws + (size_t)10 * 1024 * 1024);
  float* Bsw = (float*)(ws + (size_t)10 * 1024 * 1024 + 256 * 1024);
  float* Lp  = (float*)(ws + (size_t)10 * 1024 * 1024 + 512 * 1024);
  s16*   Xt  = (s16*)(ws + (size_t)11 * 1024 * 1024);
  s16*   Op  = (s16*)(ws + (size_t)11 * 1024 * 1024);

  hipLaunchKernelGGL(prepack2, dim3(40), dim3(256), 0, stream,
                     Wq, bq, Wk, bk, Wv, bv, Wt, Bsw);
  hipLaunchKernelGGL(xtrans, dim3(1024), dim3(256), 0, stream, x, Xt);
  hipLaunchKernelGGL(proj2, dim3(1024), dim3(256), 0, stream,
                     Xt, Wt, Bsw, Qw, Kw, Vw);
  hipLaunchKernelGGL(attn_mfma, dim3(512), dim3(512), 0, stream,
                     Qw, Kw, Vw, Op, Lp);
  hipLaunchKernelGGL(reduce_merge, dim3(2048), dim3(256), 0, stream,
                     Op, Lp, x, out);
}